// Round 1
// baseline (489.464 us; speedup 1.0000x reference)
//
#include <hip/hip_runtime.h>
#include <math.h>

#define Nn 64
#define Tt 200
#define Bb 64

__device__ __forceinline__ float sigm(float x){ return 1.0f/(1.0f+expf(-x)); }

// ---------------------------------------------------------------------------
// K1: build graph operators. L = -S_cheb, L2 = 2*S@S - I, G = S_gcn (+diag).
// Single block, 256 threads. Deterministic: per-output-column serial edge scan.
// ---------------------------------------------------------------------------
__global__ __launch_bounds__(256) void k1_graphs(
    const int* __restrict__ sp_ei, const float* __restrict__ sp_ew,
    const int* __restrict__ fn_ei, const float* __restrict__ fn_ew,
    float* __restrict__ Lg, float* __restrict__ L2g, float* __restrict__ Gm)
{
  __shared__ float dinv[Nn];
  __shared__ float S[Nn*Nn];
  __shared__ int er[1024], ec[1024];
  __shared__ float ew[1024];
  const int tid = threadIdx.x;

  // ---- ChebConv operator (512 edges) ----
  for (int e = tid; e < 512; e += 256) { er[e]=sp_ei[e]; ec[e]=sp_ei[512+e]; ew[e]=sp_ew[e]; }
  __syncthreads();
  if (tid < Nn) {
    float d = 0.f;
    for (int e=0;e<512;e++) if (er[e]==tid) d += ew[e];     // deg = segsum over row
    dinv[tid] = (d > 0.f) ? rsqrtf(d) : 0.f;
  }
  __syncthreads();
  for (int i=tid;i<Nn*Nn;i+=256) S[i]=0.f;
  __syncthreads();
  if (tid < Nn) {   // thread owns target row block S[col==tid][*]
    for (int e=0;e<512;e++) if (ec[e]==tid)
      S[tid*Nn + er[e]] += dinv[er[e]]*ew[e]*dinv[tid];
  }
  __syncthreads();
  for (int i=tid;i<Nn*Nn;i+=256) Lg[i] = -S[i];             // Ltil = -S
  for (int i=tid;i<Nn*Nn;i+=256) {
    int n=i>>6, m=i&63;
    float a=0.f;
    for (int j=0;j<Nn;j++) a += S[n*Nn+j]*S[j*Nn+m];
    L2g[i] = 2.f*a - (n==m ? 1.f : 0.f);                    // 2L^2 - I (signs cancel)
  }
  __syncthreads();

  // ---- GCNConv operator (1024 edges) ----
  for (int e = tid; e < 1024; e += 256) { er[e]=fn_ei[e]; ec[e]=fn_ei[1024+e]; ew[e]=fn_ew[e]; }
  __syncthreads();
  if (tid < Nn) {
    float d = 0.f;
    for (int e=0;e<1024;e++) if (ec[e]==tid) d += ew[e];    // deg = segsum over col, +1
    dinv[tid] = rsqrtf(d + 1.f);
  }
  __syncthreads();
  for (int i=tid;i<Nn*Nn;i+=256) S[i]=0.f;
  __syncthreads();
  if (tid < Nn) {
    for (int e=0;e<1024;e++) if (ec[e]==tid)
      S[tid*Nn + er[e]] += dinv[er[e]]*ew[e]*dinv[tid];
    S[tid*Nn + tid] += dinv[tid]*dinv[tid];                 // + diag(1/deg)
  }
  __syncthreads();
  for (int i=tid;i<Nn*Nn;i+=256) Gm[i]=S[i];
}

// ---------------------------------------------------------------------------
// K2: fold Wih (+Wcheb/Wgcn/graph ops) into Aeff[384][64] and constv[384].
// One block per output gate-row g; 64 threads.
// ---------------------------------------------------------------------------
__global__ __launch_bounds__(64) void k2_aeff(
    const float* __restrict__ Wih_f, const float* __restrict__ bih_f,
    const float* __restrict__ Wih_b, const float* __restrict__ bih_b,
    const float* __restrict__ Wcheb, const float* __restrict__ bcheb,
    const float* __restrict__ Wgcn,  const float* __restrict__ bgcn,
    const float* __restrict__ Lg, const float* __restrict__ L2g,
    const float* __restrict__ Gm,
    float* __restrict__ Aeff, float* __restrict__ constv)
{
  const int g = blockIdx.x;                 // 0..383
  const int dir = (g >= 192) ? 1 : 0;
  const int grow = dir ? g - 192 : g;
  const float* Wih = dir ? Wih_b : Wih_f;
  const float* bih = dir ? bih_b : bih_f;

  __shared__ float wrow[64*129];            // padded (stride 129) to kill bank conflicts
  __shared__ float arow[256];
  const int tid = threadIdx.x;              // 64 threads = 1 wave

  for (int i = tid; i < 8192; i += 64)
    wrow[(i>>7)*129 + (i&127)] = Wih[grow*8192 + i];
  __syncthreads();

  const int n = tid;
  float a0=0.f,a1=0.f,a2=0.f,a3=0.f,cp=0.f;
  for (int c=0;c<64;c++) {
    float w1 = wrow[n*129 + c];
    a0 = fmaf(w1, Wcheb[c],     a0);
    a1 = fmaf(w1, Wcheb[64+c],  a1);
    a2 = fmaf(w1, Wcheb[128+c], a2);
    cp = fmaf(w1, bcheb[c],     cp);
    float w2 = wrow[n*129 + 64 + c];
    a3 = fmaf(w2, Wgcn[c], a3);
    cp = fmaf(w2, bgcn[c], cp);
  }
  arow[n*4+0]=a0; arow[n*4+1]=a1; arow[n*4+2]=a2; arow[n*4+3]=a3;
  for (int off=32; off; off>>=1) cp += __shfl_down(cp, off, 64);
  if (tid==0) constv[g] = cp + bih[grow];
  __syncthreads();

  const int m = tid;
  float ae = arow[m*4+0];
  for (int nn2=0; nn2<64; nn2++) {
    ae = fmaf(arow[nn2*4+1], Lg [nn2*64+m], ae);
    ae = fmaf(arow[nn2*4+2], L2g[nn2*64+m], ae);
    ae = fmaf(arow[nn2*4+3], Gm [nn2*64+m], ae);
  }
  Aeff[g*64+m] = ae;
}

// ---------------------------------------------------------------------------
// K3: transpose x[B][N][T] -> xTr[B*T][N]  (coalesced writes)
// ---------------------------------------------------------------------------
__global__ __launch_bounds__(256) void k3_transpose(
    const float* __restrict__ x, float* __restrict__ xTr)
{
  const int b = blockIdx.x;
  for (int idx = threadIdx.x; idx < Tt*Nn; idx += 256) {
    int t = idx >> 6, m = idx & 63;
    xTr[(b*Tt + t)*64 + m] = x[(b*64 + m)*Tt + t];
  }
}

// ---------------------------------------------------------------------------
// K4: xp[12800][384] = xTr[12800][64] @ Aeff[384][64]^T + constv
// Register-tiled fp32 GEMM: 64x64 block tile, 4x4 per thread, K=64 single tile.
// ---------------------------------------------------------------------------
__global__ __launch_bounds__(256) void k4_gemm(
    const float* __restrict__ xTr, const float* __restrict__ Aeff,
    const float* __restrict__ constv, float* __restrict__ xp)
{
  const int m0 = blockIdx.x*64, g0 = blockIdx.y*64;
  __shared__ float sX[64*68];   // [k][m], stride 68 (16B-aligned rows)
  __shared__ float sA[64*68];   // [k][g]
  const int tid = threadIdx.x;
  const float4* xTr4 = (const float4*)xTr;
  const float4* A4   = (const float4*)Aeff;

  #pragma unroll
  for (int i=0;i<4;i++) {
    int f = tid + i*256;                 // 0..1023
    int row = f >> 4, kq = f & 15;
    float4 v = xTr4[(m0+row)*16 + kq];
    float vv[4] = {v.x,v.y,v.z,v.w};
    float4 w = A4[(g0+row)*16 + kq];
    float wv[4] = {w.x,w.y,w.z,w.w};
    #pragma unroll
    for (int q=0;q<4;q++) {
      sX[(kq*4+q)*68 + row] = vv[q];
      sA[(kq*4+q)*68 + row] = wv[q];
    }
  }
  __syncthreads();

  const int tm = tid & 15, tn = tid >> 4;
  float acc[4][4] = {};
  #pragma unroll 8
  for (int k=0;k<64;k++) {
    float4 a  = *(const float4*)&sX[k*68 + tm*4];
    float4 bb = *(const float4*)&sA[k*68 + tn*4];
    float av[4]={a.x,a.y,a.z,a.w}, bv[4]={bb.x,bb.y,bb.z,bb.w};
    #pragma unroll
    for (int i=0;i<4;i++)
      #pragma unroll
      for (int j=0;j<4;j++)
        acc[i][j] = fmaf(av[i], bv[j], acc[i][j]);
  }

  float cv[4];
  #pragma unroll
  for (int j=0;j<4;j++) cv[j] = constv[g0 + tn*4 + j];
  #pragma unroll
  for (int i=0;i<4;i++) {
    int mrow = m0 + tm*4 + i;
    #pragma unroll
    for (int j=0;j<4;j++)
      xp[mrow*384 + g0 + tn*4 + j] = acc[i][j] + cv[j];
  }
}

// ---------------------------------------------------------------------------
// K5: biGRU recurrence. 128 blocks = (b, dir); 192 threads, Whh row in VGPRs.
// ---------------------------------------------------------------------------
__global__ __launch_bounds__(192) void k5_gru(
    const float* __restrict__ xp,
    const float* __restrict__ Whh_f, const float* __restrict__ bhh_f,
    const float* __restrict__ Whh_b, const float* __restrict__ bhh_b,
    float* __restrict__ gru_out)
{
  const int bd = blockIdx.x;
  const int b = bd >> 1, dir = bd & 1;
  const int g = threadIdx.x;                // 0..191
  const float* Whh = dir ? Whh_b : Whh_f;
  const float* bhh = dir ? bhh_b : bhh_f;

  float wr[64];
  #pragma unroll
  for (int c=0;c<64;c++) wr[c] = Whh[g*64 + c];
  const float bh = bhh[g];
  const int goff = dir*192;

  __shared__ __align__(16) float h_s[64];
  __shared__ float hg_s[192], xg_s[192];
  if (g < 64) h_s[g] = 0.f;

  int t0 = dir ? (Tt-1) : 0;
  float xg = xp[(b*Tt + t0)*384 + goff + g];
  __syncthreads();

  const float4* h4 = (const float4*)h_s;
  for (int step=0; step<Tt; step++) {
    const int t = dir ? (Tt-1-step) : step;
    float acc = bh;
    #pragma unroll
    for (int c4=0;c4<16;c4++) {
      float4 hv = h4[c4];
      acc = fmaf(wr[c4*4+0], hv.x, acc);
      acc = fmaf(wr[c4*4+1], hv.y, acc);
      acc = fmaf(wr[c4*4+2], hv.z, acc);
      acc = fmaf(wr[c4*4+3], hv.w, acc);
    }
    hg_s[g] = acc; xg_s[g] = xg;
    if (step < Tt-1) {                      // prefetch next step's xp
      int tn = dir ? (Tt-2-step) : (step+1);
      xg = xp[(b*Tt + tn)*384 + goff + g];
    }
    __syncthreads();
    if (g < 64) {
      float r  = sigm(xg_s[g]      + hg_s[g]);
      float z  = sigm(xg_s[64+g]   + hg_s[64+g]);
      float nn = tanhf(xg_s[128+g] + r*hg_s[128+g]);
      float hnew = (1.f - z)*nn + z*h_s[g];
      h_s[g] = hnew;
      gru_out[(b*Tt + t)*128 + dir*64 + g] = hnew;
    }
    __syncthreads();
  }
}

// ---------------------------------------------------------------------------
// K6: attention pooling + classifier. One block per batch item.
// ---------------------------------------------------------------------------
__global__ __launch_bounds__(256) void k6_attn(
    const float* __restrict__ gru_out,
    const float* __restrict__ attn_W, const float* __restrict__ attn_b,
    const float* __restrict__ clf_W,  const float* __restrict__ clf_b,
    float* __restrict__ out)
{
  const int b = blockIdx.x, tid = threadIdx.x;
  __shared__ float s_s[Tt];
  __shared__ float red[256];
  __shared__ float aW[128], cW[128];
  if (tid < 128) { aW[tid]=attn_W[tid]; cW[tid]=clf_W[tid]; }
  __syncthreads();

  if (tid < Tt) {
    const float* row = gru_out + (b*Tt + tid)*128;
    float acc = 0.f;
    for (int j=0;j<128;j++) acc = fmaf(row[j], aW[j], acc);
    s_s[tid] = tanhf(acc + attn_b[0]);
  }
  __syncthreads();

  red[tid] = (tid < Tt) ? s_s[tid] : -1e30f;
  __syncthreads();
  for (int s2=128;s2;s2>>=1){ if(tid<s2) red[tid]=fmaxf(red[tid],red[tid+s2]); __syncthreads(); }
  float mx = red[0];
  __syncthreads();

  float e = 0.f;
  if (tid < Tt) { e = expf(s_s[tid]-mx); s_s[tid] = e; }
  red[tid] = e;
  __syncthreads();
  for (int s2=128;s2;s2>>=1){ if(tid<s2) red[tid]+=red[tid+s2]; __syncthreads(); }
  float total = red[0];
  __syncthreads();

  float p = 0.f;
  if (tid < 128) {
    float c = 0.f;
    for (int t=0;t<Tt;t++) c = fmaf(s_s[t], gru_out[(b*Tt+t)*128 + tid], c);
    p = (c/total)*cW[tid];
  }
  red[tid] = p;
  __syncthreads();
  for (int s2=128;s2;s2>>=1){ if(tid<s2) red[tid]+=red[tid+s2]; __syncthreads(); }
  if (tid==0) out[b] = sigm(red[0] + clf_b[0]);
}

// ---------------------------------------------------------------------------
extern "C" void kernel_launch(void* const* d_in, const int* in_sizes, int n_in,
                              void* d_out, int out_size, void* d_ws, size_t ws_size,
                              hipStream_t stream)
{
  const float* x      = (const float*)d_in[0];
  const int*   sp_ei  = (const int*)  d_in[1];
  const float* sp_ew  = (const float*)d_in[2];
  const int*   fn_ei  = (const int*)  d_in[3];
  const float* fn_ew  = (const float*)d_in[4];
  const float* Wcheb  = (const float*)d_in[5];
  const float* bcheb  = (const float*)d_in[6];
  const float* Wgcn   = (const float*)d_in[7];
  const float* bgcn   = (const float*)d_in[8];
  const float* Wih_f  = (const float*)d_in[9];
  const float* Whh_f  = (const float*)d_in[10];
  const float* bih_f  = (const float*)d_in[11];
  const float* bhh_f  = (const float*)d_in[12];
  const float* Wih_b  = (const float*)d_in[13];
  const float* Whh_b  = (const float*)d_in[14];
  const float* bih_b  = (const float*)d_in[15];
  const float* bhh_b  = (const float*)d_in[16];
  const float* attn_W = (const float*)d_in[17];
  const float* attn_b = (const float*)d_in[18];
  const float* clf_W  = (const float*)d_in[19];
  const float* clf_b  = (const float*)d_in[20];
  float* out = (float*)d_out;

  float* ws     = (float*)d_ws;
  float* Lg     = ws;                    // 4096
  float* L2g    = Lg   + 4096;           // 4096
  float* Gm     = L2g  + 4096;           // 4096
  float* Aeff   = Gm   + 4096;           // 384*64 = 24576
  float* constv = Aeff + 24576;          // 384 (+pad to 512)
  float* xTr    = constv + 512;          // 12800*64 = 819200
  float* xp     = xTr  + 819200;         // 12800*384 = 4915200
  float* gro    = xp   + 4915200;        // 12800*128 = 1638400

  hipLaunchKernelGGL(k1_graphs,    dim3(1),      dim3(256), 0, stream,
                     sp_ei, sp_ew, fn_ei, fn_ew, Lg, L2g, Gm);
  hipLaunchKernelGGL(k3_transpose, dim3(64),     dim3(256), 0, stream, x, xTr);
  hipLaunchKernelGGL(k2_aeff,      dim3(384),    dim3(64),  0, stream,
                     Wih_f, bih_f, Wih_b, bih_b, Wcheb, bcheb, Wgcn, bgcn,
                     Lg, L2g, Gm, Aeff, constv);
  hipLaunchKernelGGL(k4_gemm,      dim3(200, 6), dim3(256), 0, stream,
                     xTr, Aeff, constv, xp);
  hipLaunchKernelGGL(k5_gru,       dim3(128),    dim3(192), 0, stream,
                     xp, Whh_f, bhh_f, Whh_b, bhh_b, gro);
  hipLaunchKernelGGL(k6_attn,      dim3(64),     dim3(256), 0, stream,
                     gro, attn_W, attn_b, clf_W, clf_b, out);
}

// Round 2
// 201.991 us; speedup vs baseline: 2.4232x; 2.4232x over previous
//
#include <hip/hip_runtime.h>
#include <math.h>

#define Nn 64
#define Tt 200
#define Bb 64

__device__ __forceinline__ float sigm(float x){ return 1.0f/(1.0f+__expf(-x)); }
__device__ __forceinline__ float tanh_fast(float x){
  x = fminf(fmaxf(x, -15.f), 15.f);
  float e = __expf(-2.f*x);
  return (1.f - e)/(1.f + e);
}

typedef __attribute__((ext_vector_type(2))) float f2;
typedef __attribute__((ext_vector_type(4))) float f4;

#define PKFMA(acc, w2, h2) asm("v_pk_fma_f32 %0, %1, %2, %0" : "+v"(acc) : "v"(w2), "v"(h2))

// ---------------------------------------------------------------------------
// K1: build graph operators. L = -S_cheb, L2 = 2*S@S - I, G = S_gcn (+diag).
// Single block, 256 threads. Parallel edge scatter via LDS atomics (ds_add_f32).
// FP reorder jitter ~1e-7 << 1e-2 threshold.
// ---------------------------------------------------------------------------
__global__ __launch_bounds__(256) void k1_graphs(
    const int* __restrict__ sp_ei, const float* __restrict__ sp_ew,
    const int* __restrict__ fn_ei, const float* __restrict__ fn_ew,
    float* __restrict__ Lg, float* __restrict__ L2g, float* __restrict__ Gm)
{
  __shared__ float deg[Nn];
  __shared__ float dinv[Nn];
  __shared__ float S[Nn*Nn];
  const int tid = threadIdx.x;

  // ---- ChebConv operator (512 edges) ----
  if (tid < Nn) deg[tid] = 0.f;
  for (int i=tid;i<Nn*Nn;i+=256) S[i]=0.f;
  __syncthreads();
  for (int e=tid;e<512;e+=256) atomicAdd(&deg[sp_ei[e]], sp_ew[e]);   // deg over row
  __syncthreads();
  if (tid < Nn) dinv[tid] = (deg[tid] > 0.f) ? rsqrtf(deg[tid]) : 0.f;
  __syncthreads();
  for (int e=tid;e<512;e+=256) {
    int r = sp_ei[e], c = sp_ei[512+e];
    atomicAdd(&S[c*Nn + r], dinv[r]*sp_ew[e]*dinv[c]);
  }
  __syncthreads();
  for (int i=tid;i<Nn*Nn;i+=256) Lg[i] = -S[i];             // Ltil = -S
  #pragma unroll
  for (int k=0;k<16;k++) {                                  // L2 = 2*S@S - I
    int i = tid + k*256;
    int n = i >> 6, m = i & 63;
    float a = 0.f;
    #pragma unroll
    for (int j=0;j<Nn;j++) a = fmaf(S[n*Nn+j], S[j*Nn+m], a);
    L2g[i] = 2.f*a - (n==m ? 1.f : 0.f);
  }
  __syncthreads();   // all reads of S done before reuse

  // ---- GCNConv operator (1024 edges) ----
  if (tid < Nn) deg[tid] = 0.f;
  for (int i=tid;i<Nn*Nn;i+=256) S[i]=0.f;
  __syncthreads();
  for (int e=tid;e<1024;e+=256) atomicAdd(&deg[fn_ei[1024+e]], fn_ew[e]);  // deg over col
  __syncthreads();
  if (tid < Nn) dinv[tid] = rsqrtf(deg[tid] + 1.f);
  __syncthreads();
  for (int e=tid;e<1024;e+=256) {
    int r = fn_ei[e], c = fn_ei[1024+e];
    atomicAdd(&S[c*Nn + r], dinv[r]*fn_ew[e]*dinv[c]);
  }
  __syncthreads();
  if (tid < Nn) S[tid*Nn + tid] += dinv[tid]*dinv[tid];     // + diag(1/deg)
  __syncthreads();
  for (int i=tid;i<Nn*Nn;i+=256) Gm[i]=S[i];
}

// ---------------------------------------------------------------------------
// K2: fold Wih (+Wcheb/Wgcn/graph ops) into Aeff[384][64] and constv[384].
// One block per output gate-row g; 64 threads.
// ---------------------------------------------------------------------------
__global__ __launch_bounds__(64) void k2_aeff(
    const float* __restrict__ Wih_f, const float* __restrict__ bih_f,
    const float* __restrict__ Wih_b, const float* __restrict__ bih_b,
    const float* __restrict__ Wcheb, const float* __restrict__ bcheb,
    const float* __restrict__ Wgcn,  const float* __restrict__ bgcn,
    const float* __restrict__ Lg, const float* __restrict__ L2g,
    const float* __restrict__ Gm,
    float* __restrict__ Aeff, float* __restrict__ constv)
{
  const int g = blockIdx.x;                 // 0..383
  const int dir = (g >= 192) ? 1 : 0;
  const int grow = dir ? g - 192 : g;
  const float* Wih = dir ? Wih_b : Wih_f;
  const float* bih = dir ? bih_b : bih_f;

  __shared__ float wrow[64*129];            // padded (stride 129) to kill bank conflicts
  __shared__ float arow[256];
  const int tid = threadIdx.x;              // 64 threads = 1 wave

  for (int i = tid; i < 8192; i += 64)
    wrow[(i>>7)*129 + (i&127)] = Wih[grow*8192 + i];
  __syncthreads();

  const int n = tid;
  float a0=0.f,a1=0.f,a2=0.f,a3=0.f,cp=0.f;
  for (int c=0;c<64;c++) {
    float w1 = wrow[n*129 + c];
    a0 = fmaf(w1, Wcheb[c],     a0);
    a1 = fmaf(w1, Wcheb[64+c],  a1);
    a2 = fmaf(w1, Wcheb[128+c], a2);
    cp = fmaf(w1, bcheb[c],     cp);
    float w2 = wrow[n*129 + 64 + c];
    a3 = fmaf(w2, Wgcn[c], a3);
    cp = fmaf(w2, bgcn[c], cp);
  }
  arow[n*4+0]=a0; arow[n*4+1]=a1; arow[n*4+2]=a2; arow[n*4+3]=a3;
  for (int off=32; off; off>>=1) cp += __shfl_down(cp, off, 64);
  if (tid==0) constv[g] = cp + bih[grow];
  __syncthreads();

  const int m = tid;
  float ae = arow[m*4+0];
  for (int nn2=0; nn2<64; nn2++) {
    ae = fmaf(arow[nn2*4+1], Lg [nn2*64+m], ae);
    ae = fmaf(arow[nn2*4+2], L2g[nn2*64+m], ae);
    ae = fmaf(arow[nn2*4+3], Gm [nn2*64+m], ae);
  }
  Aeff[g*64+m] = ae;
}

// ---------------------------------------------------------------------------
// K3: transpose x[B][N][T] -> xTr[B*T][N]  (coalesced writes)
// ---------------------------------------------------------------------------
__global__ __launch_bounds__(256) void k3_transpose(
    const float* __restrict__ x, float* __restrict__ xTr)
{
  const int b = blockIdx.x;
  for (int idx = threadIdx.x; idx < Tt*Nn; idx += 256) {
    int t = idx >> 6, m = idx & 63;
    xTr[(b*Tt + t)*64 + m] = x[(b*64 + m)*Tt + t];
  }
}

// ---------------------------------------------------------------------------
// K4: xp[12800][384] = xTr[12800][64] @ Aeff[384][64]^T + constv
// Register-tiled fp32 GEMM: 64x64 block tile, 4x4 per thread, K=64 single tile.
// ---------------------------------------------------------------------------
__global__ __launch_bounds__(256) void k4_gemm(
    const float* __restrict__ xTr, const float* __restrict__ Aeff,
    const float* __restrict__ constv, float* __restrict__ xp)
{
  const int m0 = blockIdx.x*64, g0 = blockIdx.y*64;
  __shared__ float sX[64*68];   // [k][m], stride 68 (16B-aligned rows)
  __shared__ float sA[64*68];   // [k][g]
  const int tid = threadIdx.x;
  const float4* xTr4 = (const float4*)xTr;
  const float4* A4   = (const float4*)Aeff;

  #pragma unroll
  for (int i=0;i<4;i++) {
    int f = tid + i*256;                 // 0..1023
    int row = f >> 4, kq = f & 15;
    float4 v = xTr4[(m0+row)*16 + kq];
    float vv[4] = {v.x,v.y,v.z,v.w};
    float4 w = A4[(g0+row)*16 + kq];
    float wv[4] = {w.x,w.y,w.z,w.w};
    #pragma unroll
    for (int q=0;q<4;q++) {
      sX[(kq*4+q)*68 + row] = vv[q];
      sA[(kq*4+q)*68 + row] = wv[q];
    }
  }
  __syncthreads();

  const int tm = tid & 15, tn = tid >> 4;
  float acc[4][4] = {};
  #pragma unroll 8
  for (int k=0;k<64;k++) {
    float4 a  = *(const float4*)&sX[k*68 + tm*4];
    float4 bb = *(const float4*)&sA[k*68 + tn*4];
    float av[4]={a.x,a.y,a.z,a.w}, bv[4]={bb.x,bb.y,bb.z,bb.w};
    #pragma unroll
    for (int i=0;i<4;i++)
      #pragma unroll
      for (int j=0;j<4;j++)
        acc[i][j] = fmaf(av[i], bv[j], acc[i][j]);
  }

  float cv[4];
  #pragma unroll
  for (int j=0;j<4;j++) cv[j] = constv[g0 + tn*4 + j];
  #pragma unroll
  for (int i=0;i<4;i++) {
    int mrow = m0 + tm*4 + i;
    #pragma unroll
    for (int j=0;j<4;j++)
      xp[mrow*384 + g0 + tn*4 + j] = acc[i][j] + cv[j];
  }
}

// ---------------------------------------------------------------------------
// K5: biGRU recurrence. 128 blocks = (b, dir); ONE wave (64 threads).
// Thread g holds all 3 gate rows of Whh in VGPRs (192 regs); h broadcast via
// LDS with NO barriers (intra-wave ds ordering). Matvec via v_pk_fma_f32.
// ---------------------------------------------------------------------------
__global__ __launch_bounds__(64, 1) void k5_gru(
    const float* __restrict__ xp,
    const float* __restrict__ Whh_f, const float* __restrict__ bhh_f,
    const float* __restrict__ Whh_b, const float* __restrict__ bhh_b,
    float* __restrict__ gru_out)
{
  const int bd = blockIdx.x;
  const int b = bd >> 1, dir = bd & 1;
  const int g = threadIdx.x;                // 0..63, one wave
  const float* Whh = dir ? Whh_b : Whh_f;
  const float* bhh = dir ? bhh_b : bhh_f;

  f4 wr[16], wz[16], wn[16];
  #pragma unroll
  for (int j=0;j<16;j++) {
    wr[j] = ((const f4*)(Whh +        g*64))[j];
    wz[j] = ((const f4*)(Whh + (64 +g)*64))[j];
    wn[j] = ((const f4*)(Whh + (128+g)*64))[j];
  }
  const float br = bhh[g], bz = bhh[64+g], bn = bhh[128+g];

  __shared__ __align__(16) float h_s[64];
  h_s[g] = 0.f;
  float hprev = 0.f;

  const int t0 = dir ? (Tt-1) : 0;
  const int tstep = dir ? -1 : 1;
  const float* xp0 = xp + (size_t)b*Tt*384 + dir*192 + g;
  float* go0 = gru_out + (size_t)b*Tt*128 + dir*64 + g;

  float xr = xp0[t0*384], xz = xp0[t0*384 + 64], xn = xp0[t0*384 + 128];

  const f4* h4 = (const f4*)h_s;
  int t = t0;
  for (int step=0; step<Tt; step++) {
    float cxr = xr, cxz = xz, cxn = xn;
    if (step < Tt-1) {                      // prefetch next step's xp
      int tn2 = t + tstep;
      xr = xp0[tn2*384]; xz = xp0[tn2*384 + 64]; xn = xp0[tn2*384 + 128];
    }

    f2 ar0 = {0.f,0.f}, ar1 = {0.f,0.f};
    f2 az0 = {0.f,0.f}, az1 = {0.f,0.f};
    f2 an0 = {0.f,0.f}, an1 = {0.f,0.f};
    #pragma unroll
    for (int j=0;j<16;j++) {
      f4 hv = h4[j];
      f2 hlo = hv.xy, hhi = hv.zw;
      f2 wrl = wr[j].xy, wrh = wr[j].zw;
      f2 wzl = wz[j].xy, wzh = wz[j].zw;
      f2 wnl = wn[j].xy, wnh = wn[j].zw;
      PKFMA(ar0, wrl, hlo); PKFMA(ar1, wrh, hhi);
      PKFMA(az0, wzl, hlo); PKFMA(az1, wzh, hhi);
      PKFMA(an0, wnl, hlo); PKFMA(an1, wnh, hhi);
    }
    float accr = br + (ar0.x + ar0.y) + (ar1.x + ar1.y);
    float accz = bz + (az0.x + az0.y) + (az1.x + az1.y);
    float accn = bn + (an0.x + an0.y) + (an1.x + an1.y);

    float r  = sigm(cxr + accr);
    float z  = sigm(cxz + accz);
    float nn = tanh_fast(cxn + r*accn);
    float hnew = (1.f - z)*nn + z*hprev;

    h_s[g] = hnew;                          // intra-wave: no barrier needed
    hprev = hnew;
    go0[t*128] = hnew;
    t += tstep;
  }
}

// ---------------------------------------------------------------------------
// K6: attention pooling + classifier. One block per batch item.
// ---------------------------------------------------------------------------
__global__ __launch_bounds__(256) void k6_attn(
    const float* __restrict__ gru_out,
    const float* __restrict__ attn_W, const float* __restrict__ attn_b,
    const float* __restrict__ clf_W,  const float* __restrict__ clf_b,
    float* __restrict__ out)
{
  const int b = blockIdx.x, tid = threadIdx.x;
  __shared__ float s_s[Tt];
  __shared__ float red[256];
  __shared__ float aW[128], cW[128];
  if (tid < 128) { aW[tid]=attn_W[tid]; cW[tid]=clf_W[tid]; }
  __syncthreads();

  if (tid < Tt) {
    const float* row = gru_out + (b*Tt + tid)*128;
    float acc = 0.f;
    for (int j=0;j<128;j++) acc = fmaf(row[j], aW[j], acc);
    s_s[tid] = tanhf(acc + attn_b[0]);
  }
  __syncthreads();

  red[tid] = (tid < Tt) ? s_s[tid] : -1e30f;
  __syncthreads();
  for (int s2=128;s2;s2>>=1){ if(tid<s2) red[tid]=fmaxf(red[tid],red[tid+s2]); __syncthreads(); }
  float mx = red[0];
  __syncthreads();

  float e = 0.f;
  if (tid < Tt) { e = expf(s_s[tid]-mx); s_s[tid] = e; }
  red[tid] = e;
  __syncthreads();
  for (int s2=128;s2;s2>>=1){ if(tid<s2) red[tid]+=red[tid+s2]; __syncthreads(); }
  float total = red[0];
  __syncthreads();

  float p = 0.f;
  if (tid < 128) {
    float c = 0.f;
    for (int t=0;t<Tt;t++) c = fmaf(s_s[t], gru_out[(b*Tt+t)*128 + tid], c);
    p = (c/total)*cW[tid];
  }
  red[tid] = p;
  __syncthreads();
  for (int s2=128;s2;s2>>=1){ if(tid<s2) red[tid]+=red[tid+s2]; __syncthreads(); }
  if (tid==0) out[b] = sigm(red[0] + clf_b[0]);
}

// ---------------------------------------------------------------------------
extern "C" void kernel_launch(void* const* d_in, const int* in_sizes, int n_in,
                              void* d_out, int out_size, void* d_ws, size_t ws_size,
                              hipStream_t stream)
{
  const float* x      = (const float*)d_in[0];
  const int*   sp_ei  = (const int*)  d_in[1];
  const float* sp_ew  = (const float*)d_in[2];
  const int*   fn_ei  = (const int*)  d_in[3];
  const float* fn_ew  = (const float*)d_in[4];
  const float* Wcheb  = (const float*)d_in[5];
  const float* bcheb  = (const float*)d_in[6];
  const float* Wgcn   = (const float*)d_in[7];
  const float* bgcn   = (const float*)d_in[8];
  const float* Wih_f  = (const float*)d_in[9];
  const float* Whh_f  = (const float*)d_in[10];
  const float* bih_f  = (const float*)d_in[11];
  const float* bhh_f  = (const float*)d_in[12];
  const float* Wih_b  = (const float*)d_in[13];
  const float* Whh_b  = (const float*)d_in[14];
  const float* bih_b  = (const float*)d_in[15];
  const float* bhh_b  = (const float*)d_in[16];
  const float* attn_W = (const float*)d_in[17];
  const float* attn_b = (const float*)d_in[18];
  const float* clf_W  = (const float*)d_in[19];
  const float* clf_b  = (const float*)d_in[20];
  float* out = (float*)d_out;

  float* ws     = (float*)d_ws;
  float* Lg     = ws;                    // 4096
  float* L2g    = Lg   + 4096;           // 4096
  float* Gm     = L2g  + 4096;           // 4096
  float* Aeff   = Gm   + 4096;           // 384*64 = 24576
  float* constv = Aeff + 24576;          // 384 (+pad to 512)
  float* xTr    = constv + 512;          // 12800*64 = 819200
  float* xp     = xTr  + 819200;         // 12800*384 = 4915200
  float* gro    = xp   + 4915200;        // 12800*128 = 1638400

  hipLaunchKernelGGL(k1_graphs,    dim3(1),      dim3(256), 0, stream,
                     sp_ei, sp_ew, fn_ei, fn_ew, Lg, L2g, Gm);
  hipLaunchKernelGGL(k3_transpose, dim3(64),     dim3(256), 0, stream, x, xTr);
  hipLaunchKernelGGL(k2_aeff,      dim3(384),    dim3(64),  0, stream,
                     Wih_f, bih_f, Wih_b, bih_b, Wcheb, bcheb, Wgcn, bgcn,
                     Lg, L2g, Gm, Aeff, constv);
  hipLaunchKernelGGL(k4_gemm,      dim3(200, 6), dim3(256), 0, stream,
                     xTr, Aeff, constv, xp);
  hipLaunchKernelGGL(k5_gru,       dim3(128),    dim3(64),  0, stream,
                     xp, Whh_f, bhh_f, Whh_b, bhh_b, gro);
  hipLaunchKernelGGL(k6_attn,      dim3(64),     dim3(256), 0, stream,
                     gro, attn_W, attn_b, clf_W, clf_b, out);
}